// Round 4
// baseline (179.245 us; speedup 1.0000x reference)
//
#include <hip/hip_runtime.h>
#include <stdint.h>
#include <math.h>

#define DM 2048
#define NH 16
#define HD 128
#define LDQ (3 * DM)   // fused QKV row stride

typedef __bf16 bf16;
typedef __attribute__((ext_vector_type(8))) __bf16 bf16x8;
typedef __attribute__((ext_vector_type(4))) float f32x4;
typedef __attribute__((ext_vector_type(2))) unsigned int u32x2;

__device__ __forceinline__ void gload_lds16(const void* g, void* l) {
  __builtin_amdgcn_global_load_lds(
      (const __attribute__((address_space(1))) void*)g,
      (__attribute__((address_space(3))) void*)l,
      16, 0, 0);
}

__device__ __forceinline__ unsigned lds_addr(const void* p) {
  return (unsigned)(size_t)(const __attribute__((address_space(3))) void*)p;
}

template <int OFF>
__device__ __forceinline__ u32x2 tr_read(unsigned va) {
  u32x2 r;
  asm volatile("ds_read_b64_tr_b16 %0, %1 offset:%2"
               : "=v"(r) : "v"(va), "i"(OFF));
  return r;
}

#define TR4(dst, vd)                                        \
  dst[0] = tr_read<0>(vd);   dst[1] = tr_read<512>(vd);     \
  dst[2] = tr_read<1024>(vd); dst[3] = tr_read<1536>(vd);

// ---------------- fp32 -> bf16 conversion (all inputs, one launch) ----------------
__global__ __launch_bounds__(256) void cvt6(const float* xs, const float* qws,
                                            const float* kws, const float* vws,
                                            const float* ows, const float* gws,
                                            ushort* xd, ushort* w3d, ushort* owd,
                                            ushort* gwd) {
  const int y = blockIdx.y;
  const float4* s; ushort4* d; int n = (DM * DM) / 4;
  switch (y) {
    case 0: s = (const float4*)xs;  d = (ushort4*)xd;  break;
    case 1: s = (const float4*)qws; d = (ushort4*)w3d; break;
    case 2: s = (const float4*)kws; d = (ushort4*)(w3d + (size_t)DM * DM); break;
    case 3: s = (const float4*)vws; d = (ushort4*)(w3d + (size_t)2 * DM * DM); break;
    case 4: s = (const float4*)ows; d = (ushort4*)owd; break;
    default: s = (const float4*)gws; d = (ushort4*)gwd; n = (HD * HD) / 4; break;
  }
  int i = blockIdx.x * 256 + threadIdx.x;
  if (i >= n) return;
  float4 v = s[i];
  union { bf16 b[4]; ushort4 u; } r;
  r.b[0] = (bf16)v.x; r.b[1] = (bf16)v.y; r.b[2] = (bf16)v.z; r.b[3] = (bf16)v.w;
  d[i] = r.u;
}

// ---------------- deep-pipelined 256x256 GEMM (QKV projection) ----------------
// C[M=2048, N] = A[M,2048] * B[N,2048]^T, BK=32, 8 waves (2M x 4N), 512 thr.
// 4-deep LDS ring (128 KB), counted vmcnt (T4), 1 barrier/iter, setprio (T5),
// XOR-swizzle both-sides (T2 / rule 21).
__global__ __launch_bounds__(512, 1) void gemm256(const bf16* __restrict__ A,
                                                  const bf16* __restrict__ Bw,
                                                  bf16* __restrict__ C, int ldc) {
  __shared__ __align__(16) bf16 LA[4][8192];  // [buf][256 r][32 k] swizzled, 16KB each
  __shared__ __align__(16) bf16 LB[4][8192];
  const int tid = threadIdx.x;
  const int w = tid >> 6, l = tid & 63;
  const int wm = w >> 2, wn = w & 3;
  const int fr = l & 15, fg = l >> 4;
  const int bm0 = blockIdx.y * 256, bn0 = blockIdx.x * 256;

  // stage mapping: instr i in {0,1}: row r = i*128 + w*16 + (l>>2), unit u = l&3
  // LDS dest (linear) = base(i,w) + l*16 ; global source pre-inverse-swizzled.
  const int sr0 = w * 16 + (l >> 2);
  const int su = l & 3;
  const bf16* pa[2];
  const bf16* pb[2];
#pragma unroll
  for (int i = 0; i < 2; i++) {
    const int r = sr0 + i * 128;
    const int col = (su ^ (r & 3)) * 8;
    pa[i] = A + (size_t)(bm0 + r) * DM + col;
    pb[i] = Bw + (size_t)(bn0 + r) * DM + col;
  }

#define STG(buf, kt)                                                     \
  {                                                                      \
    _Pragma("unroll")                                                    \
    for (int i = 0; i < 2; i++) {                                        \
      gload_lds16(pa[i] + (kt) * 32, &LA[buf][(i * 128 + w * 16) * 32]); \
      gload_lds16(pb[i] + (kt) * 32, &LB[buf][(i * 128 + w * 16) * 32]); \
    }                                                                    \
  }

  f32x4 acc[8][4] = {};

  STG(0, 0);
  STG(1, 1);

  const int swzb = (fg ^ (fr & 3)) << 4;  // ds_read byte swizzle
  const int arow0 = wm * 128 + fr;
  const int brow0 = wn * 64 + fr;

  for (int t = 0; t < 64; ++t) {
    const int cur = t & 3;
    if (t < 62) {
      STG((t + 2) & 3, t + 2);
      asm volatile("s_waitcnt vmcnt(8)" ::: "memory");   // stage(t) landed; t+1,t+2 in flight
    } else if (t == 62) {
      asm volatile("s_waitcnt vmcnt(4)" ::: "memory");   // stage(62) landed
    } else {
      asm volatile("s_waitcnt vmcnt(0)" ::: "memory");   // stage(63) landed
    }
    __builtin_amdgcn_s_barrier();
    asm volatile("" ::: "memory");

    const char* Ab = (const char*)&LA[cur][0];
    const char* Bb = (const char*)&LB[cur][0];
    bf16x8 af[8], bfr[4];
#pragma unroll
    for (int m = 0; m < 8; m++)
      af[m] = *(const bf16x8*)(Ab + (arow0 + m * 16) * 64 + swzb);
#pragma unroll
    for (int n = 0; n < 4; n++)
      bfr[n] = *(const bf16x8*)(Bb + (brow0 + n * 16) * 64 + swzb);

    __builtin_amdgcn_s_setprio(1);
#pragma unroll
    for (int m = 0; m < 8; m++)
#pragma unroll
      for (int n = 0; n < 4; n++)
        acc[m][n] = __builtin_amdgcn_mfma_f32_16x16x32_bf16(af[m], bfr[n], acc[m][n], 0, 0, 0);
    __builtin_amdgcn_s_setprio(0);
    asm volatile("" ::: "memory");
  }

#pragma unroll
  for (int m = 0; m < 8; m++) {
    const int row0 = bm0 + wm * 128 + m * 16 + fg * 4;
#pragma unroll
    for (int n = 0; n < 4; n++) {
      const int col = bn0 + wn * 64 + n * 16 + fr;
#pragma unroll
      for (int j = 0; j < 4; j++) C[(size_t)(row0 + j) * ldc + col] = (bf16)acc[m][n][j];
    }
  }
#undef STG
}

// ---------------- GEMM: C[M,Ncols] = A[M,2048] * B[Ncols,2048]^T (out-proj) ----------------
template <typename OutT>
__global__ __launch_bounds__(256) void gemm128(const bf16* __restrict__ A,
                                               const bf16* __restrict__ Bw,
                                               OutT* __restrict__ C, int ldc) {
  __shared__ __align__(16) bf16 As[128 * 32];
  __shared__ __align__(16) bf16 Bs[128 * 32];
  const int tid = threadIdx.x;
  const int w = tid >> 6, l = tid & 63;
  const int wr = w >> 1, wc = w & 1;
  const int bx = blockIdx.x, by = blockIdx.y;
  const int lrow = l >> 2, lcol = (l & 3) * 8;
  const int fr = l & 15, fg = l >> 4;
  const bf16* Ag = A + (size_t)(by * 128 + w * 32 + lrow) * DM + lcol;
  const bf16* Bg = Bw + (size_t)(bx * 128 + w * 32 + lrow) * DM + lcol;
  bf16* Asw = &As[(w * 32) * 32];
  bf16* Bsw = &Bs[(w * 32) * 32];
  f32x4 acc[4][4] = {};
  for (int kt = 0; kt < DM / 32; ++kt) {
    const int ko = kt * 32;
    gload_lds16(Ag + ko, Asw);
    gload_lds16(Ag + ko + 16 * DM, Asw + 16 * 32);
    gload_lds16(Bg + ko, Bsw);
    gload_lds16(Bg + ko + 16 * DM, Bsw + 16 * 32);
    __syncthreads();
    bf16x8 af[4], bfr[4];
#pragma unroll
    for (int m = 0; m < 4; m++)
      af[m] = *(const bf16x8*)&As[(wr * 64 + m * 16 + fr) * 32 + fg * 8];
#pragma unroll
    for (int n = 0; n < 4; n++)
      bfr[n] = *(const bf16x8*)&Bs[(wc * 64 + n * 16 + fr) * 32 + fg * 8];
#pragma unroll
    for (int m = 0; m < 4; m++)
#pragma unroll
      for (int n = 0; n < 4; n++)
        acc[m][n] = __builtin_amdgcn_mfma_f32_16x16x32_bf16(af[m], bfr[n], acc[m][n], 0, 0, 0);
    __syncthreads();
  }
#pragma unroll
  for (int m = 0; m < 4; m++) {
    const int row0 = by * 128 + wr * 64 + m * 16 + fg * 4;
#pragma unroll
    for (int n = 0; n < 4; n++) {
      const int col = bx * 128 + wc * 64 + n * 16 + fr;
#pragma unroll
      for (int j = 0; j < 4; j++) C[(size_t)(row0 + j) * ldc + col] = (OutT)acc[m][n][j];
    }
  }
}

// ---------------- causal flash attention + fused sigmoid gate ----------------
__global__ __launch_bounds__(256, 2) void attn_k(const bf16* __restrict__ QKV,
                                                 const bf16* __restrict__ GWb,
                                                 const float* __restrict__ gbias,
                                                 bf16* __restrict__ Gout) {
  __shared__ __align__(16) bf16 Ks[2][8192];  // [buf][64 k][128 d] XOR-swizzled (16B units)
  __shared__ __align__(16) bf16 Vs[2][8192];  // [buf][8 dblk][64 k][16 d]
  const int gid = blockIdx.x;
  const int h = gid & 15;
  const int idx = gid >> 4;
  const int qt = (idx < 16) ? (31 - idx) : (idx - 16);  // complementary pairs per CU
  const int tid = threadIdx.x;
  const int w = tid >> 6, l = tid & 63;
  const int fr = l & 15, fg = l >> 4;
  const int fg4 = fg * 4;
  const int qbase = qt * 64 + w * 16;
  const int qg = qbase + fr;
  const int qcol = h * HD;
  const int kcol = DM + h * HD;
  const int vcol = 2 * DM + h * HD;
  const float scale = 0.08838834764831845f;  // 1/sqrt(128)

  bf16x8 bq[4];
#pragma unroll
  for (int kt = 0; kt < 4; kt++)
    bq[kt] = *(const bf16x8*)&QKV[(size_t)(qbase + fr) * LDQ + qcol + kt * 32 + fg * 8];

  const bf16* vbase = QKV + (size_t)(l >> 1) * LDQ + vcol + (l & 1) * 8;
  bf16* Ksl = &Ks[0][0];
  bf16* Vsl = &Vs[0][0];
  const unsigned ldsb = lds_addr(Vsl) + 8u * (unsigned)l;

#define STAGE(buf, kvbase)                                                    \
  {                                                                           \
    _Pragma("unroll")                                                         \
    for (int c = 0; c < 4; c++) {                                             \
      const int i = w * 4 + c;                                                \
      const int krow = i * 4 + (l >> 4);                                      \
      const int c16 = (l & 15) ^ (krow & 7);                                  \
      gload_lds16(QKV + (size_t)((kvbase) + krow) * LDQ + kcol + c16 * 8,     \
                  Ksl + (buf) * 8192 + i * 512);                              \
      const int db = i >> 1, k0 = (i & 1) * 32;                               \
      gload_lds16(vbase + (size_t)((kvbase) + k0) * LDQ + db * 16,            \
                  Vsl + (buf) * 8192 + db * 1024 + k0 * 16);                  \
    }                                                                         \
  }

  f32x4 oacc[8] = {};
  float m = -1e30f, lsum = 0.f;

  STAGE(0, 0);
  __syncthreads();

  for (int t = 0; t <= qt; ++t) {
    const int kv0 = t * 64;
    const int cur = t & 1;
    bf16x8 ak[4][4];
    {
      const char* Kb = (const char*)(Ksl + cur * 8192);
      const int swz = fr & 7;
#pragma unroll
      for (int kb = 0; kb < 4; kb++) {
        const char* rp = Kb + (kb * 16 + fr) * 256;
#pragma unroll
        for (int kt = 0; kt < 4; kt++)
          ak[kb][kt] = *(const bf16x8*)(rp + (((kt * 4 + fg) ^ swz) << 4));
      }
    }
    if (t < qt) STAGE(cur ^ 1, kv0 + 64);
    f32x4 sacc[4] = {};
#pragma unroll
    for (int kb = 0; kb < 4; kb++)
#pragma unroll
      for (int kt = 0; kt < 4; kt++)
        sacc[kb] = __builtin_amdgcn_mfma_f32_16x16x32_bf16(ak[kb][kt], bq[kt], sacc[kb], 0, 0, 0);
    const bool diag = (t == qt);
    float p[4][4];
    float tmax = -1e30f;
#pragma unroll
    for (int kb = 0; kb < 4; kb++)
#pragma unroll
      for (int j = 0; j < 4; j++) {
        float s = sacc[kb][j] * scale;
        if (diag && (kv0 + kb * 16 + fg4 + j) > qg) s = -1e30f;
        p[kb][j] = s;
        tmax = fmaxf(tmax, s);
      }
    tmax = fmaxf(tmax, __shfl_xor(tmax, 16, 64));
    tmax = fmaxf(tmax, __shfl_xor(tmax, 32, 64));
    const float mnew = fmaxf(m, tmax);
    const float alpha = __expf(m - mnew);
    m = mnew;
    float sum = 0.f;
#pragma unroll
    for (int kb = 0; kb < 4; kb++)
#pragma unroll
      for (int j = 0; j < 4; j++) {
        const float e = __expf(p[kb][j] - m);
        p[kb][j] = e;
        sum += e;
      }
    sum += __shfl_xor(sum, 16, 64);
    sum += __shfl_xor(sum, 32, 64);
    lsum = lsum * alpha + sum;
    float alpha4[4];
#pragma unroll
    for (int j = 0; j < 4; j++) alpha4[j] = __shfl(alpha, fg4 + j, 64);
#pragma unroll
    for (int db = 0; db < 8; db++)
#pragma unroll
      for (int j = 0; j < 4; j++) oacc[db][j] *= alpha4[j];
    bf16x8 pa[2];
#pragma unroll
    for (int kc = 0; kc < 2; kc++)
#pragma unroll
      for (int e = 0; e < 8; e++) pa[kc][e] = (bf16)p[2 * kc + (e >> 2)][e & 3];
    {
      const unsigned va = ldsb + (unsigned)cur * 16384u;
      u32x2 ta[4], tb[4];
      TR4(ta, va);
#pragma unroll
      for (int db = 0; db < 8; db++) {
        const u32x2* curp = (db & 1) ? tb : ta;
        u32x2* nxtp = (db & 1) ? ta : tb;
        if (db < 7) {
          const unsigned vd = va + (unsigned)(db + 1) * 2048u;
          TR4(nxtp, vd);
          asm volatile("s_waitcnt lgkmcnt(4)" ::: "memory");
        } else {
          asm volatile("s_waitcnt lgkmcnt(0)" ::: "memory");
        }
        __builtin_amdgcn_sched_barrier(0);
        union { u32x2 h[2]; bf16x8 v; } u0, u1;
        u0.h[0] = curp[0]; u0.h[1] = curp[1];
        u1.h[0] = curp[2]; u1.h[1] = curp[3];
        oacc[db] = __builtin_amdgcn_mfma_f32_16x16x32_bf16(pa[0], u0.v, oacc[db], 0, 0, 0);
        oacc[db] = __builtin_amdgcn_mfma_f32_16x16x32_bf16(pa[1], u1.v, oacc[db], 0, 0, 0);
      }
    }
    __syncthreads();
  }

  const float rinv = 1.0f / lsum;
  float rinv4[4];
#pragma unroll
  for (int j = 0; j < 4; j++) rinv4[j] = __shfl(rinv, fg4 + j, 64);
  f32x4 gacc[8] = {};
#pragma unroll
  for (int kt = 0; kt < 4; kt++)
#pragma unroll
    for (int eb = 0; eb < 8; eb++) {
      const bf16x8 bg = *(const bf16x8*)&GWb[(eb * 16 + fr) * HD + kt * 32 + fg * 8];
      gacc[eb] = __builtin_amdgcn_mfma_f32_16x16x32_bf16(bq[kt], bg, gacc[eb], 0, 0, 0);
    }
#pragma unroll
  for (int db = 0; db < 8; db++) {
    const int e = db * 16 + fr;
    const float bias = gbias[e];
    const int col = h * HD + e;
#pragma unroll
    for (int j = 0; j < 4; j++) {
      const float gate = 1.0f / (1.0f + __expf(-(gacc[db][j] + bias)));
      const float o = oacc[db][j] * rinv4[j] * gate;
      Gout[(size_t)(qbase + fg4 + j) * DM + col] = (bf16)o;
    }
  }
#undef STAGE
}

extern "C" void kernel_launch(void* const* d_in, const int* in_sizes, int n_in,
                              void* d_out, int out_size, void* d_ws, size_t ws_size,
                              hipStream_t stream) {
  const float* x  = (const float*)d_in[0];
  const float* qw = (const float*)d_in[1];
  const float* kw = (const float*)d_in[2];
  const float* vw = (const float*)d_in[3];
  const float* ow = (const float*)d_in[4];
  const float* gw = (const float*)d_in[5];
  const float* gb = (const float*)d_in[6];
  float* out = (float*)d_out;

  char* ws = (char*)d_ws;
  const size_t MB = 1024 * 1024;
  bf16* xb  = (bf16*)(ws + 0 * MB);    // 8 MB
  bf16* w3b = (bf16*)(ws + 8 * MB);    // 24 MB (qw,kw,vw rows 0/2048/4096)
  bf16* owb = (bf16*)(ws + 32 * MB);   // 8 MB
  bf16* gwb = (bf16*)(ws + 40 * MB);   // 32 KB
  bf16* QKV = (bf16*)(ws + 41 * MB);   // 24 MB  [2048][6144]
  bf16* Gb  = (bf16*)(ws + 65 * MB);   // 8 MB   [2048][2048]

  cvt6<<<dim3(4096, 6), 256, 0, stream>>>(x, qw, kw, vw, ow, gw,
                                          (ushort*)xb, (ushort*)w3b,
                                          (ushort*)owb, (ushort*)gwb);

  // fused QKV projection: C[2048][6144], 256^2 tiles
  gemm256<<<dim3(24, 8), 512, 0, stream>>>(xb, w3b, QKV, LDQ);

  attn_k<<<512, 256, 0, stream>>>(QKV, gwb, gb, Gb);

  gemm128<float><<<dim3(16, 16), 256, 0, stream>>>(Gb, owb, out, DM);
}

// Round 5
// 173.221 us; speedup vs baseline: 1.0348x; 1.0348x over previous
//
#include <hip/hip_runtime.h>
#include <stdint.h>
#include <math.h>

#define DM 2048
#define NH 16
#define HD 128
#define LDQ (3 * DM)   // fused QKV row stride

typedef __bf16 bf16;
typedef __attribute__((ext_vector_type(8))) __bf16 bf16x8;
typedef __attribute__((ext_vector_type(4))) float f32x4;
typedef __attribute__((ext_vector_type(2))) unsigned int u32x2;

__device__ __forceinline__ void gload_lds16(const void* g, void* l) {
  __builtin_amdgcn_global_load_lds(
      (const __attribute__((address_space(1))) void*)g,
      (__attribute__((address_space(3))) void*)l,
      16, 0, 0);
}

__device__ __forceinline__ unsigned lds_addr(const void* p) {
  return (unsigned)(size_t)(const __attribute__((address_space(3))) void*)p;
}

template <int OFF>
__device__ __forceinline__ u32x2 tr_read(unsigned va) {
  u32x2 r;
  asm volatile("ds_read_b64_tr_b16 %0, %1 offset:%2"
               : "=v"(r) : "v"(va), "i"(OFF));
  return r;
}

#define TR4(dst, vd)                                        \
  dst[0] = tr_read<0>(vd);   dst[1] = tr_read<512>(vd);     \
  dst[2] = tr_read<1024>(vd); dst[3] = tr_read<1536>(vd);

// ---------------- fp32 -> bf16 conversion (all inputs, one launch) ----------------
__global__ __launch_bounds__(256) void cvt6(const float* xs, const float* qws,
                                            const float* kws, const float* vws,
                                            const float* ows, const float* gws,
                                            ushort* xd, ushort* w3d, ushort* owd,
                                            ushort* gwd) {
  const int y = blockIdx.y;
  const float4* s; ushort4* d; int n = (DM * DM) / 4;
  switch (y) {
    case 0: s = (const float4*)xs;  d = (ushort4*)xd;  break;
    case 1: s = (const float4*)qws; d = (ushort4*)w3d; break;
    case 2: s = (const float4*)kws; d = (ushort4*)(w3d + (size_t)DM * DM); break;
    case 3: s = (const float4*)vws; d = (ushort4*)(w3d + (size_t)2 * DM * DM); break;
    case 4: s = (const float4*)ows; d = (ushort4*)owd; break;
    default: s = (const float4*)gws; d = (ushort4*)gwd; n = (HD * HD) / 4; break;
  }
  int i = blockIdx.x * 256 + threadIdx.x;
  if (i >= n) return;
  float4 v = s[i];
  union { bf16 b[4]; ushort4 u; } r;
  r.b[0] = (bf16)v.x; r.b[1] = (bf16)v.y; r.b[2] = (bf16)v.z; r.b[3] = (bf16)v.w;
  d[i] = r.u;
}

// ---------------- QKV GEMM: 256x192 tile, BK=64, 8 waves, 4-phase interleave ----
// C[2048,6144] = A[2048,2048] * B[6144,2048]^T. Grid = 256 blocks = 1/CU.
// LDS[r][u16] holds global 16B-unit (u ^ (r&7)) (conflict-free both sides).
__global__ __launch_bounds__(512, 1) void gemm_qkv(const bf16* __restrict__ A,
                                                   const bf16* __restrict__ Bw,
                                                   bf16* __restrict__ C) {
  __shared__ __align__(16) bf16 LA[2][256 * 64];  // 32KB / buf
  __shared__ __align__(16) bf16 LB[2][192 * 64];  // 24KB / buf
  const int tid = threadIdx.x;
  const int w = tid >> 6, l = tid & 63;
  const int wm = w >> 2, wn = w & 3;
  const int fr = l & 15, fg = l >> 4;
  // XCD-chunked mapping: xcd gets 8bm x 4bn patch (B panels L2-resident)
  const int bid = blockIdx.x;
  const int xcd = bid & 7, idx = bid >> 3;
  const int bm0 = (idx >> 2) * 256;
  const int bn0 = ((xcd << 2) | (idx & 3)) * 192;

  // staging source (pre-inverse-swizzled): lane l -> row +(l>>3), unit (l&7)^(l>>3)
  const int srow = l >> 3;
  const int sunit = (l & 7) ^ srow;
  const bf16* pa = A + (size_t)(bm0 + w * 32 + srow) * DM + sunit * 8;
  const bf16* pb = Bw + (size_t)(bn0 + w * 24 + srow) * DM + sunit * 8;

#define STG(buf, kt)                                                        \
  {                                                                         \
    _Pragma("unroll")                                                       \
    for (int i = 0; i < 4; i++)                                             \
      gload_lds16(pa + (size_t)i * 8 * DM + (kt) * 64,                      \
                  &LA[buf][(w * 32 + i * 8) * 64]);                         \
    _Pragma("unroll")                                                       \
    for (int i = 0; i < 3; i++)                                             \
      gload_lds16(pb + (size_t)i * 8 * DM + (kt) * 64,                      \
                  &LB[buf][(w * 24 + i * 8) * 64]);                         \
  }

  f32x4 acc[8][3] = {};

  STG(0, 0);
  STG(1, 1);
  asm volatile("s_waitcnt vmcnt(7)" ::: "memory");  // stage 0 landed
  __builtin_amdgcn_s_barrier();

  const int sw0 = ((fg) ^ (fr & 7)) << 4;        // ks=0 read swizzle (bytes)
  const int sw1 = ((4 + fg) ^ (fr & 7)) << 4;    // ks=1

  for (int t = 0; t < 32; ++t) {
    const int cur = t & 1;
    const char* Ab = (const char*)&LA[cur][0];
    const char* Bb = (const char*)&LB[cur][0];

    bf16x8 aA[4], aB[4], bA[3], bB[3];
    // ---- issue ks0 reads: bA, aA(m0-3), aB(m4-7) : 11 in flight ----
#pragma unroll
    for (int n = 0; n < 3; n++)
      bA[n] = *(const bf16x8*)(Bb + (wn * 48 + n * 16 + fr) * 128 + sw0);
#pragma unroll
    for (int m = 0; m < 4; m++)
      aA[m] = *(const bf16x8*)(Ab + (wm * 128 + m * 16 + fr) * 128 + sw0);
#pragma unroll
    for (int m = 0; m < 4; m++)
      aB[m] = *(const bf16x8*)(Ab + (wm * 128 + (m + 4) * 16 + fr) * 128 + sw0);
    __builtin_amdgcn_sched_barrier(0);
    // ---- MFMA block 1: m0-3 x ks0 (compiler waits lgkmcnt(4)) ----
    __builtin_amdgcn_s_setprio(1);
#pragma unroll
    for (int m = 0; m < 4; m++)
#pragma unroll
      for (int n = 0; n < 3; n++)
        acc[m][n] = __builtin_amdgcn_mfma_f32_16x16x32_bf16(aA[m], bA[n], acc[m][n], 0, 0, 0);
    __builtin_amdgcn_s_setprio(0);
    __builtin_amdgcn_sched_barrier(0);
    // ---- issue ks1 reads for bB + aA(m0-3) ----
#pragma unroll
    for (int n = 0; n < 3; n++)
      bB[n] = *(const bf16x8*)(Bb + (wn * 48 + n * 16 + fr) * 128 + sw1);
#pragma unroll
    for (int m = 0; m < 4; m++)
      aA[m] = *(const bf16x8*)(Ab + (wm * 128 + m * 16 + fr) * 128 + sw1);
    __builtin_amdgcn_sched_barrier(0);
    // ---- MFMA block 2: m4-7 x ks0 ----
    __builtin_amdgcn_s_setprio(1);
#pragma unroll
    for (int m = 0; m < 4; m++)
#pragma unroll
      for (int n = 0; n < 3; n++)
        acc[m + 4][n] = __builtin_amdgcn_mfma_f32_16x16x32_bf16(aB[m], bA[n], acc[m + 4][n], 0, 0, 0);
    __builtin_amdgcn_s_setprio(0);
    __builtin_amdgcn_sched_barrier(0);
    // ---- issue ks1 reads for aB(m4-7) ----
#pragma unroll
    for (int m = 0; m < 4; m++)
      aB[m] = *(const bf16x8*)(Ab + (wm * 128 + (m + 4) * 16 + fr) * 128 + sw1);
    __builtin_amdgcn_sched_barrier(0);
    // ---- MFMA block 3: m0-3 x ks1 ----
    __builtin_amdgcn_s_setprio(1);
#pragma unroll
    for (int m = 0; m < 4; m++)
#pragma unroll
      for (int n = 0; n < 3; n++)
        acc[m][n] = __builtin_amdgcn_mfma_f32_16x16x32_bf16(aA[m], bB[n], acc[m][n], 0, 0, 0);
    __builtin_amdgcn_s_setprio(0);
    __builtin_amdgcn_sched_barrier(0);
    // ---- MFMA block 4: m4-7 x ks1 ----
    __builtin_amdgcn_s_setprio(1);
#pragma unroll
    for (int m = 0; m < 4; m++)
#pragma unroll
      for (int n = 0; n < 3; n++)
        acc[m + 4][n] = __builtin_amdgcn_mfma_f32_16x16x32_bf16(aB[m], bB[n], acc[m + 4][n], 0, 0, 0);
    __builtin_amdgcn_s_setprio(0);
    __builtin_amdgcn_sched_barrier(0);

    __builtin_amdgcn_s_barrier();   // all waves done reading buf[cur]
    if (t < 30) {
      STG(cur, t + 2);              // overwrite buf[cur]; flies through iter t+1
      asm volatile("s_waitcnt vmcnt(7)" ::: "memory");  // stage(t+1) landed
    } else {
      asm volatile("s_waitcnt vmcnt(0)" ::: "memory");
    }
    __builtin_amdgcn_s_barrier();   // collective: buf[t+1] ready
  }

#pragma unroll
  for (int m = 0; m < 8; m++) {
    const int row0 = bm0 + wm * 128 + m * 16 + fg * 4;
#pragma unroll
    for (int n = 0; n < 3; n++) {
      const int col = bn0 + wn * 48 + n * 16 + fr;
#pragma unroll
      for (int j = 0; j < 4; j++) C[(size_t)(row0 + j) * LDQ + col] = (bf16)acc[m][n][j];
    }
  }
#undef STG
}

// ---------------- GEMM: C[M,Ncols] = A[M,2048] * B[Ncols,2048]^T (out-proj) ----------------
template <typename OutT>
__global__ __launch_bounds__(256) void gemm128(const bf16* __restrict__ A,
                                               const bf16* __restrict__ Bw,
                                               OutT* __restrict__ C, int ldc) {
  __shared__ __align__(16) bf16 As[128 * 32];
  __shared__ __align__(16) bf16 Bs[128 * 32];
  const int tid = threadIdx.x;
  const int w = tid >> 6, l = tid & 63;
  const int wr = w >> 1, wc = w & 1;
  const int bx = blockIdx.x, by = blockIdx.y;
  const int lrow = l >> 2, lcol = (l & 3) * 8;
  const int fr = l & 15, fg = l >> 4;
  const bf16* Ag = A + (size_t)(by * 128 + w * 32 + lrow) * DM + lcol;
  const bf16* Bg = Bw + (size_t)(bx * 128 + w * 32 + lrow) * DM + lcol;
  bf16* Asw = &As[(w * 32) * 32];
  bf16* Bsw = &Bs[(w * 32) * 32];
  f32x4 acc[4][4] = {};
  for (int kt = 0; kt < DM / 32; ++kt) {
    const int ko = kt * 32;
    gload_lds16(Ag + ko, Asw);
    gload_lds16(Ag + ko + 16 * DM, Asw + 16 * 32);
    gload_lds16(Bg + ko, Bsw);
    gload_lds16(Bg + ko + 16 * DM, Bsw + 16 * 32);
    __syncthreads();
    bf16x8 af[4], bfr[4];
#pragma unroll
    for (int m = 0; m < 4; m++)
      af[m] = *(const bf16x8*)&As[(wr * 64 + m * 16 + fr) * 32 + fg * 8];
#pragma unroll
    for (int n = 0; n < 4; n++)
      bfr[n] = *(const bf16x8*)&Bs[(wc * 64 + n * 16 + fr) * 32 + fg * 8];
#pragma unroll
    for (int m = 0; m < 4; m++)
#pragma unroll
      for (int n = 0; n < 4; n++)
        acc[m][n] = __builtin_amdgcn_mfma_f32_16x16x32_bf16(af[m], bfr[n], acc[m][n], 0, 0, 0);
    __syncthreads();
  }
#pragma unroll
  for (int m = 0; m < 4; m++) {
    const int row0 = by * 128 + wr * 64 + m * 16 + fg * 4;
#pragma unroll
    for (int n = 0; n < 4; n++) {
      const int col = bx * 128 + wc * 64 + n * 16 + fr;
#pragma unroll
      for (int j = 0; j < 4; j++) C[(size_t)(row0 + j) * ldc + col] = (OutT)acc[m][n][j];
    }
  }
}

// ---------------- causal flash attention + fused sigmoid gate ----------------
__global__ __launch_bounds__(256, 2) void attn_k(const bf16* __restrict__ QKV,
                                                 const bf16* __restrict__ GWb,
                                                 const float* __restrict__ gbias,
                                                 bf16* __restrict__ Gout) {
  __shared__ __align__(16) bf16 Ks[2][8192];  // [buf][64 k][128 d] XOR-swizzled (16B units)
  __shared__ __align__(16) bf16 Vs[2][8192];  // [buf][8 dblk][64 k][16 d]
  const int gid = blockIdx.x;
  const int h = gid & 15;
  const int idx = gid >> 4;
  const int qt = (idx < 16) ? (31 - idx) : (idx - 16);  // complementary pairs per CU
  const int tid = threadIdx.x;
  const int w = tid >> 6, l = tid & 63;
  const int fr = l & 15, fg = l >> 4;
  const int fg4 = fg * 4;
  const int qbase = qt * 64 + w * 16;
  const int qg = qbase + fr;
  const int qcol = h * HD;
  const int kcol = DM + h * HD;
  const int vcol = 2 * DM + h * HD;
  const float scale = 0.08838834764831845f;  // 1/sqrt(128)

  bf16x8 bq[4];
#pragma unroll
  for (int kt = 0; kt < 4; kt++)
    bq[kt] = *(const bf16x8*)&QKV[(size_t)(qbase + fr) * LDQ + qcol + kt * 32 + fg * 8];

  const bf16* vbase = QKV + (size_t)(l >> 1) * LDQ + vcol + (l & 1) * 8;
  bf16* Ksl = &Ks[0][0];
  bf16* Vsl = &Vs[0][0];
  const unsigned ldsb = lds_addr(Vsl) + 8u * (unsigned)l;

#define STAGE(buf, kvbase)                                                    \
  {                                                                           \
    _Pragma("unroll")                                                         \
    for (int c = 0; c < 4; c++) {                                             \
      const int i = w * 4 + c;                                                \
      const int krow = i * 4 + (l >> 4);                                      \
      const int c16 = (l & 15) ^ (krow & 7);                                  \
      gload_lds16(QKV + (size_t)((kvbase) + krow) * LDQ + kcol + c16 * 8,     \
                  Ksl + (buf) * 8192 + i * 512);                              \
      const int db = i >> 1, k0 = (i & 1) * 32;                               \
      gload_lds16(vbase + (size_t)((kvbase) + k0) * LDQ + db * 16,            \
                  Vsl + (buf) * 8192 + db * 1024 + k0 * 16);                  \
    }                                                                         \
  }

  f32x4 oacc[8] = {};
  float m = -1e30f, lsum = 0.f;

  STAGE(0, 0);
  __syncthreads();

  for (int t = 0; t <= qt; ++t) {
    const int kv0 = t * 64;
    const int cur = t & 1;
    bf16x8 ak[4][4];
    {
      const char* Kb = (const char*)(Ksl + cur * 8192);
      const int swz = fr & 7;
#pragma unroll
      for (int kb = 0; kb < 4; kb++) {
        const char* rp = Kb + (kb * 16 + fr) * 256;
#pragma unroll
        for (int kt = 0; kt < 4; kt++)
          ak[kb][kt] = *(const bf16x8*)(rp + (((kt * 4 + fg) ^ swz) << 4));
      }
    }
    if (t < qt) STAGE(cur ^ 1, kv0 + 64);
    f32x4 sacc[4] = {};
#pragma unroll
    for (int kb = 0; kb < 4; kb++)
#pragma unroll
      for (int kt = 0; kt < 4; kt++)
        sacc[kb] = __builtin_amdgcn_mfma_f32_16x16x32_bf16(ak[kb][kt], bq[kt], sacc[kb], 0, 0, 0);
    const bool diag = (t == qt);
    float p[4][4];
    float tmax = -1e30f;
#pragma unroll
    for (int kb = 0; kb < 4; kb++)
#pragma unroll
      for (int j = 0; j < 4; j++) {
        float s = sacc[kb][j] * scale;
        if (diag && (kv0 + kb * 16 + fg4 + j) > qg) s = -1e30f;
        p[kb][j] = s;
        tmax = fmaxf(tmax, s);
      }
    tmax = fmaxf(tmax, __shfl_xor(tmax, 16, 64));
    tmax = fmaxf(tmax, __shfl_xor(tmax, 32, 64));
    const float mnew = fmaxf(m, tmax);
    const float alpha = __expf(m - mnew);
    m = mnew;
    float sum = 0.f;
#pragma unroll
    for (int kb = 0; kb < 4; kb++)
#pragma unroll
      for (int j = 0; j < 4; j++) {
        const float e = __expf(p[kb][j] - m);
        p[kb][j] = e;
        sum += e;
      }
    sum += __shfl_xor(sum, 16, 64);
    sum += __shfl_xor(sum, 32, 64);
    lsum = lsum * alpha + sum;
    float alpha4[4];
#pragma unroll
    for (int j = 0; j < 4; j++) alpha4[j] = __shfl(alpha, fg4 + j, 64);
#pragma unroll
    for (int db = 0; db < 8; db++)
#pragma unroll
      for (int j = 0; j < 4; j++) oacc[db][j] *= alpha4[j];
    bf16x8 pa[2];
#pragma unroll
    for (int kc = 0; kc < 2; kc++)
#pragma unroll
      for (int e = 0; e < 8; e++) pa[kc][e] = (bf16)p[2 * kc + (e >> 2)][e & 3];
    {
      const unsigned va = ldsb + (unsigned)cur * 16384u;
      u32x2 ta[4], tb[4];
      TR4(ta, va);
#pragma unroll
      for (int db = 0; db < 8; db++) {
        const u32x2* curp = (db & 1) ? tb : ta;
        u32x2* nxtp = (db & 1) ? ta : tb;
        if (db < 7) {
          const unsigned vd = va + (unsigned)(db + 1) * 2048u;
          TR4(nxtp, vd);
          asm volatile("s_waitcnt lgkmcnt(4)" ::: "memory");
        } else {
          asm volatile("s_waitcnt lgkmcnt(0)" ::: "memory");
        }
        __builtin_amdgcn_sched_barrier(0);
        union { u32x2 h[2]; bf16x8 v; } u0, u1;
        u0.h[0] = curp[0]; u0.h[1] = curp[1];
        u1.h[0] = curp[2]; u1.h[1] = curp[3];
        oacc[db] = __builtin_amdgcn_mfma_f32_16x16x32_bf16(pa[0], u0.v, oacc[db], 0, 0, 0);
        oacc[db] = __builtin_amdgcn_mfma_f32_16x16x32_bf16(pa[1], u1.v, oacc[db], 0, 0, 0);
      }
    }
    __syncthreads();
  }

  const float rinv = 1.0f / lsum;
  float rinv4[4];
#pragma unroll
  for (int j = 0; j < 4; j++) rinv4[j] = __shfl(rinv, fg4 + j, 64);
  f32x4 gacc[8] = {};
#pragma unroll
  for (int kt = 0; kt < 4; kt++)
#pragma unroll
    for (int eb = 0; eb < 8; eb++) {
      const bf16x8 bg = *(const bf16x8*)&GWb[(eb * 16 + fr) * HD + kt * 32 + fg * 8];
      gacc[eb] = __builtin_amdgcn_mfma_f32_16x16x32_bf16(bq[kt], bg, gacc[eb], 0, 0, 0);
    }
#pragma unroll
  for (int db = 0; db < 8; db++) {
    const int e = db * 16 + fr;
    const float bias = gbias[e];
    const int col = h * HD + e;
#pragma unroll
    for (int j = 0; j < 4; j++) {
      const float gate = 1.0f / (1.0f + __expf(-(gacc[db][j] + bias)));
      const float o = oacc[db][j] * rinv4[j] * gate;
      Gout[(size_t)(qbase + fg4 + j) * DM + col] = (bf16)o;
    }
  }
#undef STAGE
}

extern "C" void kernel_launch(void* const* d_in, const int* in_sizes, int n_in,
                              void* d_out, int out_size, void* d_ws, size_t ws_size,
                              hipStream_t stream) {
  const float* x  = (const float*)d_in[0];
  const float* qw = (const float*)d_in[1];
  const float* kw = (const float*)d_in[2];
  const float* vw = (const float*)d_in[3];
  const float* ow = (const float*)d_in[4];
  const float* gw = (const float*)d_in[5];
  const float* gb = (const float*)d_in[6];
  float* out = (float*)d_out;

  char* ws = (char*)d_ws;
  const size_t MB = 1024 * 1024;
  bf16* xb  = (bf16*)(ws + 0 * MB);    // 8 MB
  bf16* w3b = (bf16*)(ws + 8 * MB);    // 24 MB (qw,kw,vw rows 0/2048/4096)
  bf16* owb = (bf16*)(ws + 32 * MB);   // 8 MB
  bf16* gwb = (bf16*)(ws + 40 * MB);   // 32 KB
  bf16* QKV = (bf16*)(ws + 41 * MB);   // 24 MB  [2048][6144]
  bf16* Gb  = (bf16*)(ws + 65 * MB);   // 8 MB   [2048][2048]

  cvt6<<<dim3(4096, 6), 256, 0, stream>>>(x, qw, kw, vw, ow, gw,
                                          (ushort*)xb, (ushort*)w3b,
                                          (ushort*)owb, (ushort*)gwb);

  // fused QKV projection: C[2048][6144], 256x192 tiles, 1 block/CU
  gemm_qkv<<<256, 512, 0, stream>>>(xb, w3b, QKV);

  attn_k<<<512, 256, 0, stream>>>(QKV, gwb, gb, Gb);

  gemm128<float><<<dim3(16, 16), 256, 0, stream>>>(Gb, owb, out, DM);
}

// Round 6
// 171.643 us; speedup vs baseline: 1.0443x; 1.0092x over previous
//
#include <hip/hip_runtime.h>
#include <stdint.h>
#include <math.h>

#define DM 2048
#define NH 16
#define HD 128
#define LDQ (3 * DM)   // fused QKV row stride

typedef __bf16 bf16;
typedef __attribute__((ext_vector_type(8))) __bf16 bf16x8;
typedef __attribute__((ext_vector_type(4))) float f32x4;
typedef __attribute__((ext_vector_type(2))) unsigned int u32x2;

__device__ __forceinline__ void gload_lds16(const void* g, void* l) {
  __builtin_amdgcn_global_load_lds(
      (const __attribute__((address_space(1))) void*)g,
      (__attribute__((address_space(3))) void*)l,
      16, 0, 0);
}

__device__ __forceinline__ unsigned lds_addr(const void* p) {
  return (unsigned)(size_t)(const __attribute__((address_space(3))) void*)p;
}

template <int OFF>
__device__ __forceinline__ u32x2 tr_read(unsigned va) {
  u32x2 r;
  asm volatile("ds_read_b64_tr_b16 %0, %1 offset:%2"
               : "=v"(r) : "v"(va), "i"(OFF));
  return r;
}

#define TR4(dst, vd)                                        \
  dst[0] = tr_read<0>(vd);   dst[1] = tr_read<512>(vd);     \
  dst[2] = tr_read<1024>(vd); dst[3] = tr_read<1536>(vd);

// ---------------- fp32 -> bf16 conversion (all inputs, one launch) ----------------
__global__ __launch_bounds__(256) void cvt6(const float* xs, const float* qws,
                                            const float* kws, const float* vws,
                                            const float* ows, const float* gws,
                                            ushort* xd, ushort* w3d, ushort* owd,
                                            ushort* gwd) {
  const int y = blockIdx.y;
  const float4* s; ushort4* d; int n = (DM * DM) / 4;
  switch (y) {
    case 0: s = (const float4*)xs;  d = (ushort4*)xd;  break;
    case 1: s = (const float4*)qws; d = (ushort4*)w3d; break;
    case 2: s = (const float4*)kws; d = (ushort4*)(w3d + (size_t)DM * DM); break;
    case 3: s = (const float4*)vws; d = (ushort4*)(w3d + (size_t)2 * DM * DM); break;
    case 4: s = (const float4*)ows; d = (ushort4*)owd; break;
    default: s = (const float4*)gws; d = (ushort4*)gwd; n = (HD * HD) / 4; break;
  }
  int i = blockIdx.x * 256 + threadIdx.x;
  if (i >= n) return;
  float4 v = s[i];
  union { bf16 b[4]; ushort4 u; } r;
  r.b[0] = (bf16)v.x; r.b[1] = (bf16)v.y; r.b[2] = (bf16)v.z; r.b[3] = (bf16)v.w;
  d[i] = r.u;
}

// ---------------- QKV GEMM: 256x192 tile, BK=64, 8 waves, read-ahead pipeline ----
// C[2048,6144] = A[2048,2048] * B[6144,2048]^T. Grid = 256 blocks = 1/CU.
// LDS[r][u16] holds global 16B-unit (u ^ (r&7)). Register loads pipelined one
// phase ahead of their MFMA cluster (counted lgkmcnt 11/11/4/0, FIFO DS queue).
__global__ __launch_bounds__(512, 2) void gemm_qkv(const bf16* __restrict__ A,
                                                   const bf16* __restrict__ Bw,
                                                   bf16* __restrict__ C) {
  __shared__ __align__(16) bf16 LA[2][256 * 64];  // 32KB / buf
  __shared__ __align__(16) bf16 LB[2][192 * 64];  // 24KB / buf
  const int tid = threadIdx.x;
  const int w = tid >> 6, l = tid & 63;
  const int wm = w >> 2, wn = w & 3;
  const int fr = l & 15, fg = l >> 4;
  // XCD-chunked mapping: xcd gets 8bm x 4bn patch (B panels L2-resident)
  const int bid = blockIdx.x;
  const int xcd = bid & 7, idx = bid >> 3;
  const int bm0 = (idx >> 2) * 256;
  const int bn0 = ((xcd << 2) | (idx & 3)) * 192;

  // staging source (pre-inverse-swizzled): lane l -> row +(l>>3), unit (l&7)^(l>>3)
  const int srow = l >> 3;
  const int sunit = (l & 7) ^ srow;
  const bf16* pa = A + (size_t)(bm0 + w * 32 + srow) * DM + sunit * 8;
  const bf16* pb = Bw + (size_t)(bn0 + w * 24 + srow) * DM + sunit * 8;

#define STG(buf, kt)                                                        \
  {                                                                         \
    _Pragma("unroll")                                                       \
    for (int i = 0; i < 4; i++)                                             \
      gload_lds16(pa + (size_t)i * 8 * DM + (kt) * 64,                      \
                  &LA[buf][(w * 32 + i * 8) * 64]);                         \
    _Pragma("unroll")                                                       \
    for (int i = 0; i < 3; i++)                                             \
      gload_lds16(pb + (size_t)i * 8 * DM + (kt) * 64,                      \
                  &LB[buf][(w * 24 + i * 8) * 64]);                         \
  }

  f32x4 acc[8][3] = {};

  STG(0, 0);
  STG(1, 1);
  asm volatile("s_waitcnt vmcnt(7)" ::: "memory");  // stage 0 landed
  __builtin_amdgcn_s_barrier();

  const int sw0 = ((fg) ^ (fr & 7)) << 4;        // ks=0 read swizzle (bytes)
  const int sw1 = ((4 + fg) ^ (fr & 7)) << 4;    // ks=1
  const char* AB = (const char*)&LA[0][0];
  const char* BB = (const char*)&LB[0][0];
  const int aoff = (wm * 128 + fr) * 128;   // A fragment row base (bytes)
  const int boff = (wn * 48 + fr) * 128;    // B fragment row base (bytes)

  bf16x8 bA[3], bB[3], aP[4], aQ[4], aR[4], aS[4];

  // prologue reads (R0: bA+aP = 7, R1: aQ = 4) from buf 0
#pragma unroll
  for (int n = 0; n < 3; n++) bA[n] = *(const bf16x8*)(BB + boff + n * 2048 + sw0);
#pragma unroll
  for (int m = 0; m < 4; m++) aP[m] = *(const bf16x8*)(AB + aoff + m * 2048 + sw0);
#pragma unroll
  for (int m = 0; m < 4; m++) aQ[m] = *(const bf16x8*)(AB + aoff + (m + 4) * 2048 + sw0);
  __builtin_amdgcn_sched_barrier(0);

  for (int t = 0; t < 32; ++t) {
    const int cur = t & 1;
    const char* Ac = AB + cur * 32768;
    const char* Bc = BB + cur * 24576;
    // ---- R2 (ks1: bB + aR, 7 reads) ----
#pragma unroll
    for (int n = 0; n < 3; n++) bB[n] = *(const bf16x8*)(Bc + boff + n * 2048 + sw1);
#pragma unroll
    for (int m = 0; m < 4; m++) aR[m] = *(const bf16x8*)(Ac + aoff + m * 2048 + sw1);
    asm volatile("s_waitcnt lgkmcnt(11)" ::: "memory");  // R0 done
    __builtin_amdgcn_sched_barrier(0);
    __builtin_amdgcn_s_setprio(1);
#pragma unroll
    for (int m = 0; m < 4; m++)
#pragma unroll
      for (int n = 0; n < 3; n++)
        acc[m][n] = __builtin_amdgcn_mfma_f32_16x16x32_bf16(aP[m], bA[n], acc[m][n], 0, 0, 0);
    __builtin_amdgcn_s_setprio(0);
    __builtin_amdgcn_sched_barrier(0);
    // ---- R3 (ks1: aS, 4 reads) ----
#pragma unroll
    for (int m = 0; m < 4; m++) aS[m] = *(const bf16x8*)(Ac + aoff + (m + 4) * 2048 + sw1);
    asm volatile("s_waitcnt lgkmcnt(11)" ::: "memory");  // R1 done
    __builtin_amdgcn_sched_barrier(0);
    __builtin_amdgcn_s_setprio(1);
#pragma unroll
    for (int m = 0; m < 4; m++)
#pragma unroll
      for (int n = 0; n < 3; n++)
        acc[m + 4][n] = __builtin_amdgcn_mfma_f32_16x16x32_bf16(aQ[m], bA[n], acc[m + 4][n], 0, 0, 0);
    __builtin_amdgcn_s_setprio(0);
    __builtin_amdgcn_sched_barrier(0);
    asm volatile("s_waitcnt lgkmcnt(4)" ::: "memory");   // R2 done
    __builtin_amdgcn_sched_barrier(0);
    __builtin_amdgcn_s_setprio(1);
#pragma unroll
    for (int m = 0; m < 4; m++)
#pragma unroll
      for (int n = 0; n < 3; n++)
        acc[m][n] = __builtin_amdgcn_mfma_f32_16x16x32_bf16(aR[m], bB[n], acc[m][n], 0, 0, 0);
    __builtin_amdgcn_s_setprio(0);
    __builtin_amdgcn_sched_barrier(0);
    asm volatile("s_waitcnt lgkmcnt(0)" ::: "memory");   // R3 done (all reads drained)
    __builtin_amdgcn_sched_barrier(0);
    __builtin_amdgcn_s_setprio(1);
#pragma unroll
    for (int m = 0; m < 4; m++)
#pragma unroll
      for (int n = 0; n < 3; n++)
        acc[m + 4][n] = __builtin_amdgcn_mfma_f32_16x16x32_bf16(aS[m], bB[n], acc[m + 4][n], 0, 0, 0);
    __builtin_amdgcn_s_setprio(0);
    __builtin_amdgcn_sched_barrier(0);

    __builtin_amdgcn_s_barrier();   // all waves' reads of buf[cur] complete
    if (t < 30) {
      STG(cur, t + 2);              // overwrite buf[cur]
      asm volatile("s_waitcnt vmcnt(7)" ::: "memory");  // stage(t+1) landed
    } else {
      asm volatile("s_waitcnt vmcnt(0)" ::: "memory");
    }
    __builtin_amdgcn_s_barrier();   // collective: buf for iter t+1 ready
    // ---- R0+R1 for iter t+1 (11 reads, fly under barrier exit / R2 issue) ----
    if (t < 31) {
      const char* An = AB + (cur ^ 1) * 32768;
      const char* Bn = BB + (cur ^ 1) * 24576;
#pragma unroll
      for (int n = 0; n < 3; n++) bA[n] = *(const bf16x8*)(Bn + boff + n * 2048 + sw0);
#pragma unroll
      for (int m = 0; m < 4; m++) aP[m] = *(const bf16x8*)(An + aoff + m * 2048 + sw0);
#pragma unroll
      for (int m = 0; m < 4; m++) aQ[m] = *(const bf16x8*)(An + aoff + (m + 4) * 2048 + sw0);
    }
    __builtin_amdgcn_sched_barrier(0);
  }

#pragma unroll
  for (int m = 0; m < 8; m++) {
    const int row0 = bm0 + wm * 128 + m * 16 + fg * 4;
#pragma unroll
    for (int n = 0; n < 3; n++) {
      const int col = bn0 + wn * 48 + n * 16 + fr;
#pragma unroll
      for (int j = 0; j < 4; j++) C[(size_t)(row0 + j) * LDQ + col] = (bf16)acc[m][n][j];
    }
  }
#undef STG
}

// ---------------- GEMM: C[M,Ncols] = A[M,2048] * B[Ncols,2048]^T (out-proj) ----------------
template <typename OutT>
__global__ __launch_bounds__(256) void gemm128(const bf16* __restrict__ A,
                                               const bf16* __restrict__ Bw,
                                               OutT* __restrict__ C, int ldc) {
  __shared__ __align__(16) bf16 As[128 * 32];
  __shared__ __align__(16) bf16 Bs[128 * 32];
  const int tid = threadIdx.x;
  const int w = tid >> 6, l = tid & 63;
  const int wr = w >> 1, wc = w & 1;
  const int bx = blockIdx.x, by = blockIdx.y;
  const int lrow = l >> 2, lcol = (l & 3) * 8;
  const int fr = l & 15, fg = l >> 4;
  const bf16* Ag = A + (size_t)(by * 128 + w * 32 + lrow) * DM + lcol;
  const bf16* Bg = Bw + (size_t)(bx * 128 + w * 32 + lrow) * DM + lcol;
  bf16* Asw = &As[(w * 32) * 32];
  bf16* Bsw = &Bs[(w * 32) * 32];
  f32x4 acc[4][4] = {};
  for (int kt = 0; kt < DM / 32; ++kt) {
    const int ko = kt * 32;
    gload_lds16(Ag + ko, Asw);
    gload_lds16(Ag + ko + 16 * DM, Asw + 16 * 32);
    gload_lds16(Bg + ko, Bsw);
    gload_lds16(Bg + ko + 16 * DM, Bsw + 16 * 32);
    __syncthreads();
    bf16x8 af[4], bfr[4];
#pragma unroll
    for (int m = 0; m < 4; m++)
      af[m] = *(const bf16x8*)&As[(wr * 64 + m * 16 + fr) * 32 + fg * 8];
#pragma unroll
    for (int n = 0; n < 4; n++)
      bfr[n] = *(const bf16x8*)&Bs[(wc * 64 + n * 16 + fr) * 32 + fg * 8];
#pragma unroll
    for (int m = 0; m < 4; m++)
#pragma unroll
      for (int n = 0; n < 4; n++)
        acc[m][n] = __builtin_amdgcn_mfma_f32_16x16x32_bf16(af[m], bfr[n], acc[m][n], 0, 0, 0);
    __syncthreads();
  }
#pragma unroll
  for (int m = 0; m < 4; m++) {
    const int row0 = by * 128 + wr * 64 + m * 16 + fg * 4;
#pragma unroll
    for (int n = 0; n < 4; n++) {
      const int col = bx * 128 + wc * 64 + n * 16 + fr;
#pragma unroll
      for (int j = 0; j < 4; j++) C[(size_t)(row0 + j) * ldc + col] = (OutT)acc[m][n][j];
    }
  }
}

// ---------------- causal flash attention + fused sigmoid gate ----------------
__global__ __launch_bounds__(256, 2) void attn_k(const bf16* __restrict__ QKV,
                                                 const bf16* __restrict__ GWb,
                                                 const float* __restrict__ gbias,
                                                 bf16* __restrict__ Gout) {
  __shared__ __align__(16) bf16 Ks[2][8192];  // [buf][64 k][128 d] XOR-swizzled (16B units)
  __shared__ __align__(16) bf16 Vs[2][8192];  // [buf][8 dblk][64 k][16 d]
  const int gid = blockIdx.x;
  const int h = gid & 15;
  const int idx = gid >> 4;
  const int qt = (idx < 16) ? (31 - idx) : (idx - 16);  // complementary pairs per CU
  const int tid = threadIdx.x;
  const int w = tid >> 6, l = tid & 63;
  const int fr = l & 15, fg = l >> 4;
  const int fg4 = fg * 4;
  const int qbase = qt * 64 + w * 16;
  const int qg = qbase + fr;
  const int qcol = h * HD;
  const int kcol = DM + h * HD;
  const int vcol = 2 * DM + h * HD;
  const float scale = 0.08838834764831845f;  // 1/sqrt(128)

  bf16x8 bq[4];
#pragma unroll
  for (int kt = 0; kt < 4; kt++)
    bq[kt] = *(const bf16x8*)&QKV[(size_t)(qbase + fr) * LDQ + qcol + kt * 32 + fg * 8];

  const bf16* vbase = QKV + (size_t)(l >> 1) * LDQ + vcol + (l & 1) * 8;
  bf16* Ksl = &Ks[0][0];
  bf16* Vsl = &Vs[0][0];
  const unsigned ldsb = lds_addr(Vsl) + 8u * (unsigned)l;

#define STAGE(buf, kvbase)                                                    \
  {                                                                           \
    _Pragma("unroll")                                                         \
    for (int c = 0; c < 4; c++) {                                             \
      const int i = w * 4 + c;                                                \
      const int krow = i * 4 + (l >> 4);                                      \
      const int c16 = (l & 15) ^ (krow & 7);                                  \
      gload_lds16(QKV + (size_t)((kvbase) + krow) * LDQ + kcol + c16 * 8,     \
                  Ksl + (buf) * 8192 + i * 512);                              \
      const int db = i >> 1, k0 = (i & 1) * 32;                               \
      gload_lds16(vbase + (size_t)((kvbase) + k0) * LDQ + db * 16,            \
                  Vsl + (buf) * 8192 + db * 1024 + k0 * 16);                  \
    }                                                                         \
  }

  f32x4 oacc[8] = {};
  float m = -1e30f, lsum = 0.f;

  STAGE(0, 0);
  __syncthreads();

  for (int t = 0; t <= qt; ++t) {
    const int kv0 = t * 64;
    const int cur = t & 1;
    bf16x8 ak[4][4];
    {
      const char* Kb = (const char*)(Ksl + cur * 8192);
      const int swz = fr & 7;
#pragma unroll
      for (int kb = 0; kb < 4; kb++) {
        const char* rp = Kb + (kb * 16 + fr) * 256;
#pragma unroll
        for (int kt = 0; kt < 4; kt++)
          ak[kb][kt] = *(const bf16x8*)(rp + (((kt * 4 + fg) ^ swz) << 4));
      }
    }
    if (t < qt) STAGE(cur ^ 1, kv0 + 64);
    f32x4 sacc[4] = {};
#pragma unroll
    for (int kb = 0; kb < 4; kb++)
#pragma unroll
      for (int kt = 0; kt < 4; kt++)
        sacc[kb] = __builtin_amdgcn_mfma_f32_16x16x32_bf16(ak[kb][kt], bq[kt], sacc[kb], 0, 0, 0);
    const bool diag = (t == qt);
    float p[4][4];
    float tmax = -1e30f;
#pragma unroll
    for (int kb = 0; kb < 4; kb++)
#pragma unroll
      for (int j = 0; j < 4; j++) {
        float s = sacc[kb][j] * scale;
        if (diag && (kv0 + kb * 16 + fg4 + j) > qg) s = -1e30f;
        p[kb][j] = s;
        tmax = fmaxf(tmax, s);
      }
    tmax = fmaxf(tmax, __shfl_xor(tmax, 16, 64));
    tmax = fmaxf(tmax, __shfl_xor(tmax, 32, 64));
    const float mnew = fmaxf(m, tmax);
    const float alpha = __expf(m - mnew);
    m = mnew;
    float sum = 0.f;
#pragma unroll
    for (int kb = 0; kb < 4; kb++)
#pragma unroll
      for (int j = 0; j < 4; j++) {
        const float e = __expf(p[kb][j] - m);
        p[kb][j] = e;
        sum += e;
      }
    sum += __shfl_xor(sum, 16, 64);
    sum += __shfl_xor(sum, 32, 64);
    lsum = lsum * alpha + sum;
    float alpha4[4];
#pragma unroll
    for (int j = 0; j < 4; j++) alpha4[j] = __shfl(alpha, fg4 + j, 64);
#pragma unroll
    for (int db = 0; db < 8; db++)
#pragma unroll
      for (int j = 0; j < 4; j++) oacc[db][j] *= alpha4[j];
    bf16x8 pa[2];
#pragma unroll
    for (int kc = 0; kc < 2; kc++)
#pragma unroll
      for (int e = 0; e < 8; e++) pa[kc][e] = (bf16)p[2 * kc + (e >> 2)][e & 3];
    {
      const unsigned va = ldsb + (unsigned)cur * 16384u;
      u32x2 ta[4], tb[4];
      TR4(ta, va);
#pragma unroll
      for (int db = 0; db < 8; db++) {
        const u32x2* curp = (db & 1) ? tb : ta;
        u32x2* nxtp = (db & 1) ? ta : tb;
        if (db < 7) {
          const unsigned vd = va + (unsigned)(db + 1) * 2048u;
          TR4(nxtp, vd);
          asm volatile("s_waitcnt lgkmcnt(4)" ::: "memory");
        } else {
          asm volatile("s_waitcnt lgkmcnt(0)" ::: "memory");
        }
        __builtin_amdgcn_sched_barrier(0);
        union { u32x2 h[2]; bf16x8 v; } u0, u1;
        u0.h[0] = curp[0]; u0.h[1] = curp[1];
        u1.h[0] = curp[2]; u1.h[1] = curp[3];
        oacc[db] = __builtin_amdgcn_mfma_f32_16x16x32_bf16(pa[0], u0.v, oacc[db], 0, 0, 0);
        oacc[db] = __builtin_amdgcn_mfma_f32_16x16x32_bf16(pa[1], u1.v, oacc[db], 0, 0, 0);
      }
    }
    __syncthreads();
  }

  const float rinv = 1.0f / lsum;
  float rinv4[4];
#pragma unroll
  for (int j = 0; j < 4; j++) rinv4[j] = __shfl(rinv, fg4 + j, 64);
  f32x4 gacc[8] = {};
#pragma unroll
  for (int kt = 0; kt < 4; kt++)
#pragma unroll
    for (int eb = 0; eb < 8; eb++) {
      const bf16x8 bg = *(const bf16x8*)&GWb[(eb * 16 + fr) * HD + kt * 32 + fg * 8];
      gacc[eb] = __builtin_amdgcn_mfma_f32_16x16x32_bf16(bq[kt], bg, gacc[eb], 0, 0, 0);
    }
#pragma unroll
  for (int db = 0; db < 8; db++) {
    const int e = db * 16 + fr;
    const float bias = gbias[e];
    const int col = h * HD + e;
#pragma unroll
    for (int j = 0; j < 4; j++) {
      const float gate = 1.0f / (1.0f + __expf(-(gacc[db][j] + bias)));
      const float o = oacc[db][j] * rinv4[j] * gate;
      Gout[(size_t)(qbase + fg4 + j) * DM + col] = (bf16)o;
    }
  }
#undef STAGE
}

extern "C" void kernel_launch(void* const* d_in, const int* in_sizes, int n_in,
                              void* d_out, int out_size, void* d_ws, size_t ws_size,
                              hipStream_t stream) {
  const float* x  = (const float*)d_in[0];
  const float* qw = (const float*)d_in[1];
  const float* kw = (const float*)d_in[2];
  const float* vw = (const float*)d_in[3];
  const float* ow = (const float*)d_in[4];
  const float* gw = (const float*)d_in[5];
  const float* gb = (const float*)d_in[6];
  float* out = (float*)d_out;

  char* ws = (char*)d_ws;
  const size_t MB = 1024 * 1024;
  bf16* xb  = (bf16*)(ws + 0 * MB);    // 8 MB
  bf16* w3b = (bf16*)(ws + 8 * MB);    // 24 MB (qw,kw,vw rows 0/2048/4096)
  bf16* owb = (bf16*)(ws + 32 * MB);   // 8 MB
  bf16* gwb = (bf16*)(ws + 40 * MB);   // 32 KB
  bf16* QKV = (bf16*)(ws + 41 * MB);   // 24 MB  [2048][6144]
  bf16* Gb  = (bf16*)(ws + 65 * MB);   // 8 MB   [2048][2048]

  cvt6<<<dim3(4096, 6), 256, 0, stream>>>(x, qw, kw, vw, ow, gw,
                                          (ushort*)xb, (ushort*)w3b,
                                          (ushort*)owb, (ushort*)gwb);

  // fused QKV projection: C[2048][6144], 256x192 tiles, 1 block/CU
  gemm_qkv<<<256, 512, 0, stream>>>(xb, w3b, QKV);

  attn_k<<<512, 256, 0, stream>>>(QKV, gwb, gb, Gb);

  gemm128<float><<<dim3(16, 16), 256, 0, stream>>>(Gb, owb, out, DM);
}